// Round 12
// baseline (255.985 us; speedup 1.0000x reference)
//
#include <hip/hip_runtime.h>

// PolyAttention on MI355X (gfx950).
// k_prep -> fused QKV GEMM (256x256, BK=64, 8-phase half-tile pipeline with
// derived per-phase stage slots + vmcnt(4) gates, swizzled LDS, rope fused,
// V transposed) -> causal poly^4 attention -> output GEMM.
// b=2, n=2048, d=2048, h=16, hd=128.

typedef __bf16 bf16;
typedef __bf16 bf16x8 __attribute__((ext_vector_type(8)));
typedef __bf16 bf16x4 __attribute__((ext_vector_type(4)));
typedef float f32x4 __attribute__((ext_vector_type(4)));

#define GLD(g, l)                                                   \
  __builtin_amdgcn_global_load_lds(                                 \
      (const __attribute__((address_space(1))) void*)(g),           \
      (__attribute__((address_space(3))) void*)(l), 16, 0, 0)

#define MFMA(a, b, c) __builtin_amdgcn_mfma_f32_16x16x32_bf16(a, b, c, 0, 0, 0)

// ---------- fused prep: cvt x / wqkv / wo (f32->bf16) + rope cos/sin table ----
__global__ __launch_bounds__(256) void k_prep(
    const float* __restrict__ x, const float* __restrict__ Wq,
    const float* __restrict__ Wk, const float* __restrict__ Wv,
    const float* __restrict__ Wo, bf16* __restrict__ xb,
    bf16* __restrict__ wqkv, bf16* __restrict__ wob,
    float* __restrict__ ct, float* __restrict__ st) {
  const int b = blockIdx.x, tid = threadIdx.x;
  if (b < 8192) {
    int i = b * 256 + tid;
    float4 v = reinterpret_cast<const float4*>(x)[i];
    bf16x4 o = {(bf16)v.x, (bf16)v.y, (bf16)v.z, (bf16)v.w};
    reinterpret_cast<bf16x4*>(xb)[i] = o;
  } else if (b < 20480) {
    int i = (b - 8192) * 256 + tid;
    const float* src = (i < 1048576) ? Wq : ((i < 2097152) ? Wk : Wv);
    float4 v = reinterpret_cast<const float4*>(src)[i & 1048575];
    bf16x4 o = {(bf16)v.x, (bf16)v.y, (bf16)v.z, (bf16)v.w};
    reinterpret_cast<bf16x4*>(wqkv)[i] = o;
  } else if (b < 24576) {
    int i = (b - 20480) * 256 + tid;
    float4 v = reinterpret_cast<const float4*>(Wo)[i];
    bf16x4 o = {(bf16)v.x, (bf16)v.y, (bf16)v.z, (bf16)v.w};
    reinterpret_cast<bf16x4*>(wob)[i] = o;
  } else {
    int i = (b - 24576) * 256 + tid;
    int pos = i >> 6, f = i & 63;
    float theta = exp2f(-(float)f * 0.20762050593046014f);
    float ang = (float)pos * theta;
    ct[i] = cosf(ang);
    st[i] = sinf(ang);
  }
}

// ---------- fused QKV GEMM: 256x256 tile, BK=64, 8-phase pipeline ----------
// 8 waves (2M x 4N), per-wave 128x64 (acc[8][4]). LDS 128KB: 2 bufs x
// {A0,A1,B0,B1} halves of 16KB. Even tiles (buf0) consume B in ph1-2, A by
// ph4; odd tiles (buf1) consume A in ph5-6, B by ph8. Stage slots (derived,
// WAR-safe): ph1:B0(u+1) ph2:B1(u+1) ph3:B0(u+2) ph4:B1(u+2) ph5:A0(u+2)
// ph6:A1(u+2) ph7:A0(u+3) ph8:A1(u+3). Gates vmcnt(4) at ph4/ph8 only.
__global__ __launch_bounds__(512, 1) void k_gemm_qkv(
    const bf16* __restrict__ Am, const bf16* __restrict__ Bm,
    bf16* __restrict__ Qp, bf16* __restrict__ Kp, bf16* __restrict__ Vt,
    const float* __restrict__ ct, const float* __restrict__ st) {
  __shared__ __align__(16) char LDS[131072];
  const int tid = threadIdx.x, l = tid & 63, w = tid >> 6;
  const int lr = l & 15, g = l >> 4, lr7 = lr & 7;
  const int wm = w >> 2, wn = w & 3;
  // 384 blocks; XCD k owns N-strips 3k..3k+2 (3MB of B -> its L2)
  const int swz = (blockIdx.x & 7) * 48 + (blockIdx.x >> 3);
  const int tm = (swz & 15) * 256;
  const int tn = (swz >> 4) * 256;

  // stage source (inverse-swizzled): dest row j=tid>>3, slot s=tid&7 holds
  // global chunk s^(j&7)
  const int srow = tid >> 3;
  const int ssw = ((tid & 7) ^ (srow & 7)) << 3;  // elements

#define STAGE_A8(bufoff, h, kt)                                              \
  {                                                                          \
    GLD(Am + (size_t)(tm + (h) * 128 + srow) * 2048 + (kt) + ssw,            \
        LDS + (bufoff) + (h) * 16384 + tid * 16);                            \
    GLD(Am + (size_t)(tm + (h) * 128 + 64 + srow) * 2048 + (kt) + ssw,       \
        LDS + (bufoff) + (h) * 16384 + 8192 + tid * 16);                     \
  }
#define STAGE_B8(bufoff, h, kt)                                              \
  {                                                                          \
    GLD(Bm + (size_t)(tn + (h) * 128 + srow) * 2048 + (kt) + ssw,            \
        LDS + (bufoff) + 32768 + (h) * 16384 + tid * 16);                    \
    GLD(Bm + (size_t)(tn + (h) * 128 + 64 + srow) * 2048 + (kt) + ssw,       \
        LDS + (bufoff) + 32768 + (h) * 16384 + 8192 + tid * 16);             \
  }

  // ds-read bases (bytes, within a buffer)
  const int x0 = ((0 + g) ^ lr7) << 4;   // kk=0 chunk
  const int x1 = ((4 + g) ^ lr7) << 4;   // kk=1 chunk
  const int Ab = wm * 16384 + lr * 128;                         // + fm*2048 + x
  const int Bb = 32768 + (wn >> 1) * 16384 + ((wn & 1) * 64 + lr) * 128;  // + nf*2048 + x

  f32x4 acc[8][4] = {};

  // prologue: tile0 full (buf0) + tile1 A (buf1)
  STAGE_A8(0, 0, 0); STAGE_A8(0, 1, 0);
  STAGE_B8(0, 0, 0); STAGE_B8(0, 1, 0);
  STAGE_A8(65536, 0, 64); STAGE_A8(65536, 1, 64);
  asm volatile("s_waitcnt vmcnt(4)" ::: "memory");
  __builtin_amdgcn_s_barrier();

  for (int i = 0; i < 16; ++i) {
    const int u = 2 * i;
    const int kodd = (u + 1) * 64;
    const int ks2 = (u + 2 < 32 ? u + 2 : 31) * 64;
    const int ks3 = (u + 3 < 32 ? u + 3 : 31) * 64;
    const char* B0 = LDS;            // even tile buffer
    const char* B1 = LDS + 65536;    // odd tile buffer
    bf16x8 a[4], a2[4], bK0[4], bK1[4];

    // ======== even tile u (buf0): B early, A late ========
    // ph1: fm0-3 x nf0-3 x kk0
#pragma unroll
    for (int nf = 0; nf < 4; ++nf)
      bK0[nf] = *reinterpret_cast<const bf16x8*>(B0 + Bb + nf * 2048 + x0);
#pragma unroll
    for (int fm = 0; fm < 4; ++fm)
      a[fm] = *reinterpret_cast<const bf16x8*>(B0 + Ab + fm * 2048 + x0);
    STAGE_B8(65536, 0, kodd);
    __builtin_amdgcn_s_barrier();
    __builtin_amdgcn_s_setprio(1);
#pragma unroll
    for (int fm = 0; fm < 4; ++fm)
#pragma unroll
      for (int nf = 0; nf < 4; ++nf)
        acc[fm][nf] = MFMA(a[fm], bK0[nf], acc[fm][nf]);
    __builtin_amdgcn_s_setprio(0);
    __builtin_amdgcn_s_barrier();

    // ph2: fm0-3 x nf0-3 x kk1
#pragma unroll
    for (int nf = 0; nf < 4; ++nf)
      bK1[nf] = *reinterpret_cast<const bf16x8*>(B0 + Bb + nf * 2048 + x1);
#pragma unroll
    for (int fm = 0; fm < 4; ++fm)
      a2[fm] = *reinterpret_cast<const bf16x8*>(B0 + Ab + fm * 2048 + x1);
    STAGE_B8(65536, 1, kodd);
    __builtin_amdgcn_s_barrier();
    __builtin_amdgcn_s_setprio(1);
#pragma unroll
    for (int fm = 0; fm < 4; ++fm)
#pragma unroll
      for (int nf = 0; nf < 4; ++nf)
        acc[fm][nf] = MFMA(a2[fm], bK1[nf], acc[fm][nf]);
    __builtin_amdgcn_s_setprio(0);
    __builtin_amdgcn_s_barrier();

    // ph3: fm4-7 x nf0-3 x kk0
#pragma unroll
    for (int fm = 0; fm < 4; ++fm)
      a[fm] = *reinterpret_cast<const bf16x8*>(B0 + Ab + (fm + 4) * 2048 + x0);
    STAGE_B8(0, 0, ks2);
    __builtin_amdgcn_s_barrier();
    __builtin_amdgcn_s_setprio(1);
#pragma unroll
    for (int fm = 0; fm < 4; ++fm)
#pragma unroll
      for (int nf = 0; nf < 4; ++nf)
        acc[fm + 4][nf] = MFMA(a[fm], bK0[nf], acc[fm + 4][nf]);
    __builtin_amdgcn_s_setprio(0);
    __builtin_amdgcn_s_barrier();

    // ph4: fm4-7 x nf0-3 x kk1  + GATE
#pragma unroll
    for (int fm = 0; fm < 4; ++fm)
      a2[fm] = *reinterpret_cast<const bf16x8*>(B0 + Ab + (fm + 4) * 2048 + x1);
    STAGE_B8(0, 1, ks2);
    __builtin_amdgcn_s_barrier();
    __builtin_amdgcn_s_setprio(1);
#pragma unroll
    for (int fm = 0; fm < 4; ++fm)
#pragma unroll
      for (int nf = 0; nf < 4; ++nf)
        acc[fm + 4][nf] = MFMA(a2[fm], bK1[nf], acc[fm + 4][nf]);
    __builtin_amdgcn_s_setprio(0);
    asm volatile("s_waitcnt vmcnt(4)" ::: "memory");  // tile u+1 fully landed
    __builtin_amdgcn_s_barrier();

    // ======== odd tile u+1 (buf1): A early, B late ========
    bf16x8 aA[8], aB[8], bo[2];
    // ph5: fm0-7 x nf0-1 x kk0
#pragma unroll
    for (int fm = 0; fm < 8; ++fm)
      aA[fm] = *reinterpret_cast<const bf16x8*>(B1 + Ab + fm * 2048 + x0);
    bo[0] = *reinterpret_cast<const bf16x8*>(B1 + Bb + x0);
    bo[1] = *reinterpret_cast<const bf16x8*>(B1 + Bb + 2048 + x0);
    STAGE_A8(0, 0, ks2);
    __builtin_amdgcn_s_barrier();
    __builtin_amdgcn_s_setprio(1);
#pragma unroll
    for (int fm = 0; fm < 8; ++fm) {
      acc[fm][0] = MFMA(aA[fm], bo[0], acc[fm][0]);
      acc[fm][1] = MFMA(aA[fm], bo[1], acc[fm][1]);
    }
    __builtin_amdgcn_s_setprio(0);
    __builtin_amdgcn_s_barrier();

    // ph6: fm0-7 x nf0-1 x kk1
#pragma unroll
    for (int fm = 0; fm < 8; ++fm)
      aB[fm] = *reinterpret_cast<const bf16x8*>(B1 + Ab + fm * 2048 + x1);
    bo[0] = *reinterpret_cast<const bf16x8*>(B1 + Bb + x1);
    bo[1] = *reinterpret_cast<const bf16x8*>(B1 + Bb + 2048 + x1);
    STAGE_A8(0, 1, ks2);
    __builtin_amdgcn_s_barrier();
    __builtin_amdgcn_s_setprio(1);
#pragma unroll
    for (int fm = 0; fm < 8; ++fm) {
      acc[fm][0] = MFMA(aB[fm], bo[0], acc[fm][0]);
      acc[fm][1] = MFMA(aB[fm], bo[1], acc[fm][1]);
    }
    __builtin_amdgcn_s_setprio(0);
    __builtin_amdgcn_s_barrier();

    // ph7: fm0-7 x nf2-3 x kk0
    bo[0] = *reinterpret_cast<const bf16x8*>(B1 + Bb + 2 * 2048 + x0);
    bo[1] = *reinterpret_cast<const bf16x8*>(B1 + Bb + 3 * 2048 + x0);
    STAGE_A8(65536, 0, ks3);
    __builtin_amdgcn_s_barrier();
    __builtin_amdgcn_s_setprio(1);
#pragma unroll
    for (int fm = 0; fm < 8; ++fm) {
      acc[fm][2] = MFMA(aA[fm], bo[0], acc[fm][2]);
      acc[fm][3] = MFMA(aA[fm], bo[1], acc[fm][3]);
    }
    __builtin_amdgcn_s_setprio(0);
    __builtin_amdgcn_s_barrier();

    // ph8: fm0-7 x nf2-3 x kk1  + GATE
    bo[0] = *reinterpret_cast<const bf16x8*>(B1 + Bb + 2 * 2048 + x1);
    bo[1] = *reinterpret_cast<const bf16x8*>(B1 + Bb + 3 * 2048 + x1);
    STAGE_A8(65536, 1, ks3);
    __builtin_amdgcn_s_barrier();
    __builtin_amdgcn_s_setprio(1);
#pragma unroll
    for (int fm = 0; fm < 8; ++fm) {
      acc[fm][2] = MFMA(aB[fm], bo[0], acc[fm][2]);
      acc[fm][3] = MFMA(aB[fm], bo[1], acc[fm][3]);
    }
    __builtin_amdgcn_s_setprio(0);
    asm volatile("s_waitcnt vmcnt(4)" ::: "memory");  // tile u+2 B+A landed
    __builtin_amdgcn_s_barrier();
  }

  asm volatile("s_waitcnt vmcnt(0)" ::: "memory");  // drain tail dummy stages
  __builtin_amdgcn_s_barrier();

  // ---- epilogue (round-5 form, verified) ----
  if (tn < 4096) {
    bf16* dst = (tn < 2048) ? Qp : Kp;
    const int nb = tn & 2047;
    bf16* E = (bf16*)LDS;  // [128][264]
    for (int pass = 0; pass < 2; ++pass) {
      __syncthreads();
      if (wm == pass) {
#pragma unroll
        for (int fm = 0; fm < 8; ++fm)
#pragma unroll
          for (int nf = 0; nf < 4; ++nf)
#pragma unroll
            for (int rr = 0; rr < 4; ++rr)
              E[(fm * 16 + g * 4 + rr) * 264 + wn * 64 + nf * 16 + lr] =
                  (bf16)acc[fm][nf][rr];
      }
      __syncthreads();
#pragma unroll
      for (int it = 0; it < 8; ++it) {
        int task = it * 512 + tid;  // 128 rows x 2 heads x 16 d4-groups
        int row = task >> 5, rem = task & 31;
        int hd = rem >> 4, dg = (rem & 15) << 2;
        int token = tm + pass * 128 + row;
        int nn = token & 2047, bb = token >> 11;
        f32x4 c4 = *reinterpret_cast<const f32x4*>(ct + nn * 64 + dg);
        f32x4 s4 = *reinterpret_cast<const f32x4*>(st + nn * 64 + dg);
        bf16x4 x1v = *reinterpret_cast<const bf16x4*>(E + row * 264 + hd * 128 + dg);
        bf16x4 x2v = *reinterpret_cast<const bf16x4*>(E + row * 264 + hd * 128 + 64 + dg);
        bf16x4 o1, o2;
#pragma unroll
        for (int j = 0; j < 4; ++j) {
          float a1 = (float)x1v[j], a2v = (float)x2v[j];
          o1[j] = (bf16)(a1 * c4[j] - a2v * s4[j]);
          o2[j] = (bf16)(a1 * s4[j] + a2v * c4[j]);
        }
        int h_ = (nb >> 7) + hd;
        size_t rb = (((size_t)bb * 16 + h_) * 2048 + nn) * 128;
        *reinterpret_cast<bf16x4*>(dst + rb + dg) = o1;
        *reinterpret_cast<bf16x4*>(dst + rb + 64 + dg) = o2;
      }
    }
  } else {
#pragma unroll
    for (int fm = 0; fm < 8; ++fm)
#pragma unroll
      for (int nf = 0; nf < 4; ++nf) {
        int row0 = tm + wm * 128 + fm * 16 + g * 4;
        int col = (tn - 4096) + wn * 64 + nf * 16 + lr;
        int bb = row0 >> 11, nn = row0 & 2047;
        int hh = col >> 7, dd = col & 127;
        bf16x4 o = {(bf16)acc[fm][nf][0], (bf16)acc[fm][nf][1],
                    (bf16)acc[fm][nf][2], (bf16)acc[fm][nf][3]};
        *reinterpret_cast<bf16x4*>(
            Vt + (((size_t)bb * 16 + hh) * 128 + dd) * 2048 + nn) = o;
      }
  }
}

// ---------- output GEMM: C(f32) = A*B^T, 4096x2048x2048 (round-11, kept) ----------
__global__ __launch_bounds__(256, 2) void k_gemm_out(const bf16* __restrict__ Am,
                                                     const bf16* __restrict__ Bm,
                                                     float* __restrict__ C) {
  __shared__ __align__(16) char LDS[73728];
  const int tid = threadIdx.x, w = tid >> 6, l = tid & 63;
  const int lr = l & 15, g = l >> 4;
  const int wr = w >> 1, wc = w & 1;
  const int tm = blockIdx.y * 256, tn = blockIdx.x * 128;

  const int rl = tid >> 2;
  const int scol = (((tid & 3) ^ (rl & 3) ^ ((rl >> 2) & 3)) << 3);
  const int xo = ((g ^ (lr & 3) ^ ((lr >> 2) & 3)) << 4);

#define STAGEU(buf, kt)                                                      \
  {                                                                          \
    _Pragma("unroll") for (int i = 0; i < 4; ++i)                            \
        GLD(Am + (size_t)(tm + i * 64 + rl) * 2048 + (kt) + scol,            \
            LDS + (buf) * 24576 + i * 4096 + tid * 16);                      \
    _Pragma("unroll") for (int i = 0; i < 2; ++i)                            \
        GLD(Bm + (size_t)(tn + i * 64 + rl) * 2048 + (kt) + scol,            \
            LDS + (buf) * 24576 + 16384 + i * 4096 + tid * 16);              \
  }

  f32x4 acc[8][4] = {};

  STAGEU(0, 0);
  STAGEU(1, 32);
  int cur = 0, st3 = 2;
  for (int t = 0; t < 63; ++t) {
    asm volatile("s_waitcnt vmcnt(6)" ::: "memory");
    __builtin_amdgcn_s_barrier();
    asm volatile("" ::: "memory");
    if (t < 62) STAGEU(st3, (t + 2) * 32);
    const char* pa = LDS + cur * 24576;
    const char* pb = pa + 16384;
    bf16x8 a[8], b[4];
#pragma unroll
    for (int fm = 0; fm < 8; ++fm)
      a[fm] = *reinterpret_cast<const bf16x8*>(pa + (wr * 128 + fm * 16 + lr) * 64 + xo);
#pragma unroll
    for (int nf = 0; nf < 4; ++nf)
      b[nf] = *reinterpret_cast<const bf16x8*>(pb + (wc * 64 + nf * 16 + lr) * 64 + xo);
    __builtin_amdgcn_s_setprio(1);
#pragma unroll
    for (int fm = 0; fm < 8; ++fm)
#pragma unroll
      for (int nf = 0; nf < 4; ++nf)
        acc[fm][nf] = MFMA(a[fm], b[nf], acc[fm][nf]);
    __builtin_amdgcn_s_setprio(0);
    cur = (cur == 2) ? 0 : cur + 1;
    st3 = (st3 == 2) ? 0 : st3 + 1;
  }
  {
    asm volatile("s_waitcnt vmcnt(0)" ::: "memory");
    __builtin_amdgcn_s_barrier();
    asm volatile("" ::: "memory");
    const char* pa = LDS + cur * 24576;
    const char* pb = pa + 16384;
    bf16x8 a[8], b[4];
#pragma unroll
    for (int fm = 0; fm < 8; ++fm)
      a[fm] = *reinterpret_cast<const bf16x8*>(pa + (wr * 128 + fm * 16 + lr) * 64 + xo);
#pragma unroll
    for (int nf = 0; nf < 4; ++nf)
      b[nf] = *reinterpret_cast<const bf16x8*>(pb + (wc * 64 + nf * 16 + lr) * 64 + xo);
#pragma unroll
    for (int fm = 0; fm < 8; ++fm)
#pragma unroll
      for (int nf = 0; nf < 4; ++nf)
        acc[fm][nf] = MFMA(a[fm], b[nf], acc[fm][nf]);
  }

#pragma unroll
  for (int fm = 0; fm < 8; ++fm)
#pragma unroll
    for (int nf = 0; nf < 4; ++nf)
#pragma unroll
      for (int rr = 0; rr < 4; ++rr) {
        int row = tm + wr * 128 + fm * 16 + g * 4 + rr;
        int col = tn + wc * 64 + nf * 16 + lr;
        C[(size_t)row * 2048 + col] = acc[fm][nf][rr];
      }
}

// ---------- causal poly^4 attention (round-10 version, frozen) ----------
__global__ __launch_bounds__(256) void k_attn(const bf16* __restrict__ Q,
                                              const bf16* __restrict__ K,
                                              const bf16* __restrict__ Vt,
                                              bf16* __restrict__ O) {
  __shared__ __align__(16) bf16 Ks[2][64 * 128];
  __shared__ __align__(16) bf16 Vs[2][128 * 64];
  __shared__ __align__(16) bf16 Ps[128 * 64];
  const int tid = threadIdx.x, w = tid >> 6, l = tid & 63;
  const int lr = l & 15, g = l >> 4;
  const int qb = 15 - (blockIdx.x >> 5);
  const int bh = blockIdx.x & 31;
  const size_t base = (size_t)bh * 2048 * 128;
  const int b_ = bh >> 4, h_ = bh & 15;
  const int qbase = qb * 128;
  const int nt = 2 * qb + 2;

  bf16x8 vones = {};
  if (lr == 0) {
#pragma unroll
    for (int j = 0; j < 8; ++j) vones[j] = (bf16)1.0f;
  }

  bf16x8 qf[2][4];
#pragma unroll
  for (int mi = 0; mi < 2; ++mi)
#pragma unroll
    for (int kc = 0; kc < 4; ++kc)
      qf[mi][kc] = *reinterpret_cast<const bf16x8*>(
          Q + base + (size_t)(qbase + w * 32 + mi * 16 + lr) * 128 + kc * 32 + g * 8);

  f32x4 on[2][8] = {};
  f32x4 dn4[2] = {};

#define STAGEKV(tt, buf)                                                 \
  {                                                                      \
    const bf16* kg = K + base + (size_t)(tt) * 64 * 128;                 \
    _Pragma("unroll") for (int r = 0; r < 4; ++r) {                      \
      int row = r * 16 + w * 4 + (l >> 4);                               \
      int cc = l & 15;                                                   \
      GLD(kg + (row << 7) + ((cc ^ (row & 7)) << 3),                     \
          Ks[buf] + r * 2048 + w * 512);                                 \
    }                                                                    \
    const bf16* vg = Vt + base + (tt) * 64;                              \
    _Pragma("unroll") for (int r = 0; r < 4; ++r) {                      \
      int row = r * 32 + w * 8 + (l >> 3);                               \
      int cc = l & 7;                                                    \
      GLD(vg + (size_t)row * 2048 + ((cc ^ (row & 7)) << 3),             \
          Vs[buf] + r * 2048 + w * 512);                                 \
    }                                                                    \
  }

  STAGEKV(0, 0);

  for (int t = 0; t < nt; ++t) {
    int tn1 = (t + 1 < nt) ? t + 1 : nt - 1;
    STAGEKV(tn1, (t + 1) & 1);
    asm volatile("s_waitcnt vmcnt(8)" ::: "memory");
    __builtin_amdgcn_s_barrier();

    const bf16* kcur = Ks[t & 1];
    const bf16* vcur = Vs[t & 1];

    f32x4 s[2][4] = {};
    __builtin_amdgcn_s_setprio(1);
#pragma unroll
    for (int kc = 0; kc < 4; ++kc) {
      bf16x8 kb[4];
#pragma unroll
      for (int ni = 0; ni < 4; ++ni)
        kb[ni] = *reinterpret_cast<const bf16x8*>(
            kcur + ((ni * 16 + lr) << 7) + (((kc * 4 + g) ^ (lr & 7)) << 3));
#pragma unroll
      for (int mi = 0; mi < 2; ++mi)
#pragma unroll
        for (int ni = 0; ni < 4; ++ni)
          s[mi][ni] = MFMA(qf[mi][kc], kb[ni], s[mi][ni]);
    }
    __builtin_amdgcn_s_setprio(0);

#pragma unroll
    for (int mi = 0; mi < 2; ++mi) {
      const bool msk = (t * 64 + 63 > qbase + w * 32 + mi * 16);
#pragma unroll
      for (int ni = 0; ni < 4; ++ni)
#pragma unroll
        for (int r = 0; r < 4; ++r) {
          int lrow = mi * 16 + g * 4 + r;
          float v = s[mi][ni][r];
          if (msk) {
            int qrow = qbase + w * 32 + lrow;
            int col = t * 64 + ni * 16 + lr;
            v = (col <= qrow) ? v : 0.f;
          }
          float v2 = v * v, v4 = v2 * v2;
          Ps[((w * 32 + lrow) << 6) +
             (((ni * 2 + (lr >> 3)) ^ (lrow & 7)) << 3) + (lr & 7)] = (bf16)v4;
        }
    }

    __builtin_amdgcn_s_setprio(1);
#pragma unroll
    for (int k2 = 0; k2 < 2; ++k2) {
      bf16x8 pa[2];
#pragma unroll
      for (int mi = 0; mi < 2; ++mi)
        pa[mi] = *reinterpret_cast<const bf16x8*>(
            Ps + ((w * 32 + mi * 16 + lr) << 6) + (((k2 * 4 + g) ^ (lr & 7)) << 3));
      dn4[0] = MFMA(pa[0], vones, dn4[0]);
      dn4[1] = MFMA(pa[1], vones, dn4[1]);
#pragma unroll
      for (int ni = 0; ni < 8; ++ni) {
        bf16x8 vbf = *reinterpret_cast<const bf16x8*>(
            vcur + ((ni * 16 + lr) << 6) + (((k2 * 4 + g) ^ (lr & 7)) << 3));
        on[0][ni] = MFMA(pa[0], vbf, on[0][ni]);
        on[1][ni] = MFMA(pa[1], vbf, on[1][ni]);
      }
    }
    __builtin_amdgcn_s_setprio(0);
    __builtin_amdgcn_s_barrier();
  }

  asm volatile("s_waitcnt vmcnt(0)" ::: "memory");

#pragma unroll
  for (int mi = 0; mi < 2; ++mi)
#pragma unroll
    for (int r = 0; r < 4; ++r) {
      float d = __shfl(dn4[mi][r], l & 48);
      float inv = 1.0f / fmaxf(d, 1e-6f);
      int row = qbase + w * 32 + mi * 16 + g * 4 + r;
#pragma unroll
      for (int ni = 0; ni < 8; ++ni)
        O[((size_t)b_ * 2048 + row) * 2048 + h_ * 128 + ni * 16 + lr] =
            (bf16)(on[mi][ni][r] * inv);
    }
#undef STAGEKV
}

extern "C" void kernel_launch(void* const* d_in, const int* in_sizes, int n_in,
                              void* d_out, int out_size, void* d_ws, size_t ws_size,
                              hipStream_t stream) {
  const float* x  = (const float*)d_in[0];
  const float* Wq = (const float*)d_in[1];
  const float* Wk = (const float*)d_in[2];
  const float* Wv = (const float*)d_in[3];
  const float* Wo = (const float*)d_in[4];
  float* out = (float*)d_out;

  char* p = (char*)d_ws;
  bf16* xb   = (bf16*)p; p += (size_t)8388608 * 2;
  bf16* wqkv = (bf16*)p; p += (size_t)12582912 * 2;
  bf16* wob  = (bf16*)p; p += (size_t)4194304 * 2;
  bf16* Qp   = (bf16*)p; p += (size_t)8388608 * 2;
  bf16* Kp   = (bf16*)p; p += (size_t)8388608 * 2;
  bf16* Vt   = (bf16*)p; p += (size_t)8388608 * 2;
  bf16* Ob   = (bf16*)p; p += (size_t)8388608 * 2;
  float* ct  = (float*)p; p += (size_t)131072 * 4;
  float* st  = (float*)p; p += (size_t)131072 * 4;

  k_prep<<<25088, 256, 0, stream>>>(x, Wq, Wk, Wv, Wo, xb, wqkv, wob, ct, st);

  k_gemm_qkv<<<384, 512, 0, stream>>>(xb, wqkv, Qp, Kp, Vt, ct, st);

  k_attn<<<512, 256, 0, stream>>>(Qp, Kp, Vt, Ob);

  k_gemm_out<<<dim3(16, 16), 256, 0, stream>>>(Ob, wob, out);
}